// Round 12
// baseline (438.565 us; speedup 1.0000x reference)
//
#include <hip/hip_runtime.h>
#include <cstdint>
#include <math.h>

// ---------------------------------------------------------------------------
// ParallelAttention (GPT-NeoX style), MI355X gfx950.
//   SEQ=2048 BATCH=2 HID=2048 NH=16 HD=128, causal mask, RoPE full head dim.
// INTERFACE (established R0-R7): fp32 inputs, fp32 output, inputs resolved by
//   element count (w_dense = LAST 4194304 match; mask unused).
// R9: GEMMs on m97 structure (bf16 pre-convert + global_load_lds w16).
// R11/R15/R16: attn single-buffer + XCD-locality swizzle (FETCH 110->25MB).
// R17: 8-wave/512-thr attn (16 waves/CU) -> attn ~100us; merged qkv; 422.1.
// R18 FAILED: split-K dense w/ atomicAdd (16.7M RMW) -> 458.
// R19 FAILED: dense BN=64 -> ~155us (worse than BN=128's 137): halved MFMA
//   per K-step (16->8) but staging only 8->6 gl16 -> worse compute:barrier
//   ratio. Rule: keep the 128x128 tile's 16:8 ratio; add blocks another way.
// R20: dense SPLIT-K=2, plain stores: grid (16,32,2) = 1024 blocks = 4/CU
//   (m102: this structure at 1024 blocks hits 833 TF vs ~320 grid-starved).
//   Inner loop byte-identical to R17 dense. z=0 -> out; z=1 -> po f32
//   partial at ws[16M,48M) (Kw+wb dead after attn; 4096x2048x4B = 32MiB
//   exactly, ends at ctx base). combine: out += po (~100MB, ~16us).
//   No atomics (R18's killer), no thin tiles (R19's killer).
// MFMA 16x16x32 bf16: A/B row=lane&15, k=(lane>>4)*8+j; C/D col=lane&15,
//   row=(lane>>4)*4+reg (verified m89/m91).
// global_load_lds: LDS dest is wave-uniform base + lane*16B (m104/m108) --
//   LDS must be LINEAR, source address is per-lane (pre-swizzle there).
// ---------------------------------------------------------------------------

typedef unsigned short u16;
typedef __bf16 bf16x8 __attribute__((ext_vector_type(8)));
typedef float floatx4 __attribute__((ext_vector_type(4)));

#define SEQ 2048
#define BATCH 2
#define HID 2048
#define NH 16
#define HD 128

__device__ __forceinline__ u16 f2bf(float f) {
  union { float f; uint32_t u; } v; v.f = f;
  uint32_t u = v.u;
  return (u16)((u + 0x7FFFu + ((u >> 16) & 1u)) >> 16);
}

// pack 8 fp32 -> 8 bf16 (RNE) and store 16B
__device__ __forceinline__ void st8_bf16(u16* dst, const float* s) {
  uint32_t pk[4];
#pragma unroll
  for (int j = 0; j < 4; j++)
    pk[j] = (uint32_t)f2bf(s[2 * j]) | ((uint32_t)f2bf(s[2 * j + 1]) << 16);
  *(uint4*)dst = make_uint4(pk[0], pk[1], pk[2], pk[3]);
}

// async global->LDS, 16B per lane; lds base must be wave-uniform
__device__ __forceinline__ void gl16(const u16* g, u16* l) {
  __builtin_amdgcn_global_load_lds(
      (const __attribute__((address_space(1))) void*)g,
      (__attribute__((address_space(3))) void*)l, 16, 0, 0);
}

// ------- input conversion: w_qkv K/Q tiles, hidden, V tiles; + bias tail ----
// wb tile order: [K head 0..15][Q head 0..15]; src K h = 3h+1, Q h = 3h.
// V tiles (blk 8192..10239) -> wvw (d_out scratch). blk 10240 = bias tail.
__global__ __launch_bounds__(256) void cvt_inputs(
    const float* __restrict__ W, const float* __restrict__ Hid,
    u16* __restrict__ wb, u16* __restrict__ Ah, u16* __restrict__ wvw,
    const float* __restrict__ bd, float* __restrict__ out) {
  const int blk = blockIdx.x;
  const int c0 = threadIdx.x * 8;
  if (blk == 10240) {  // bias passthrough: fp32 -> out tail (never clobbered)
#pragma unroll
    for (int j = 0; j < 8; j++)
      out[(size_t)SEQ * BATCH * HID + c0 + j] = bd[c0 + j];
    return;
  }
  const float* src;
  u16* dst;
  if (blk < 4096) {
    int dt = blk >> 7, r = blk & 127;
    int srow = (dt < 16) ? ((dt * 3 + 1) * 128 + r) : (((dt - 16) * 3) * 128 + r);
    src = W + (size_t)srow * HID;
    dst = wb + (size_t)blk * HID;
  } else if (blk < 8192) {
    int r = blk - 4096;
    src = Hid + (size_t)r * HID;
    dst = Ah + (size_t)r * HID;
  } else {
    int v = blk - 8192;  // 0..2047
    int h = v >> 7, r = v & 127;
    src = W + (size_t)((h * 3 + 2) * 128 + r) * HID;
    dst = wvw + (size_t)v * HID;
  }
  float t[8];
  *(floatx4*)&t[0] = *(const floatx4*)(src + c0);
  *(floatx4*)&t[4] = *(const floatx4*)(src + c0 + 4);
  st8_bf16(dst + c0, t);
}

// ---------------- w_dense fp32 -> bf16 (after attn: wd aliases Qw) ----------
__global__ __launch_bounds__(256) void cvt_wd(const float* __restrict__ W,
                                              u16* __restrict__ wd) {
  const int r = blockIdx.x;
  const int c0 = threadIdx.x * 8;
  float t[8];
  const float* src = W + (size_t)r * HID;
  *(floatx4*)&t[0] = *(const floatx4*)(src + c0);
  *(floatx4*)&t[4] = *(const floatx4*)(src + c0 + 4);
  st8_bf16(wd + (size_t)r * HID + c0, t);
}

// ------- QKV projection (merged): bf16 @ bf16, gload_lds both operands ------
// blockIdx.x 0..15 = K head, 16..31 = Q head, 32..47 = V head.
__global__ __launch_bounds__(256, 2) void qkv(
    const u16* __restrict__ Ah, const u16* __restrict__ wb,
    const u16* __restrict__ wvw, const float* __restrict__ bias,
    u16* __restrict__ Qw, u16* __restrict__ Kw, u16* __restrict__ Vt) {
  __shared__ __align__(16) u16 As[128 * 64];
  __shared__ __align__(16) u16 Bs[128 * 64];
  const int tid = threadIdx.x;
  const int wv = tid >> 6, lane = tid & 63;
  const int quad = lane >> 4, l16 = lane & 15;
  const int wt = blockIdx.x;  // 0..47
  const bool isv = (wt >= 32);
  const int bm = blockIdx.y;
  const int rowA0 = bm * 128;
  const int wm = (wv >> 1) * 64;
  const int wn = (wv & 1) * 32;
  const int ntoff[4] = {wn, wn + 16, wn + 64, wn + 80};

  const int lrow = wv * 32 + (lane >> 3);
  const int lcol = (lane & 7) * 8;
  const u16* Ag = Ah + (size_t)(rowA0 + lrow) * HID + lcol;
  const u16* Bg = (isv ? wvw + ((size_t)(wt - 32) * 128 + lrow) * HID
                       : wb + ((size_t)wt * 128 + lrow) * HID) + lcol;
  u16* Al = &As[(wv * 32) * 64];  // wave-uniform
  u16* Bl = &Bs[(wv * 32) * 64];

  floatx4 acc[4][4];
#pragma unroll
  for (int i = 0; i < 4; i++)
#pragma unroll
    for (int j = 0; j < 4; j++) acc[i][j] = (floatx4){0.f, 0.f, 0.f, 0.f};

  for (int kb = 0; kb < HID; kb += 64) {
#pragma unroll
    for (int j = 0; j < 4; j++) {
      gl16(Ag + (size_t)j * 8 * HID + kb, Al + j * 8 * 64);
      gl16(Bg + (size_t)j * 8 * HID + kb, Bl + j * 8 * 64);
    }
    __syncthreads();  // drains vmcnt(0): LDS tiles ready
#pragma unroll
    for (int ks = 0; ks < 64; ks += 32) {
      bf16x8 af[4], bfr[4];
#pragma unroll
      for (int mi = 0; mi < 4; mi++)
        af[mi] = *(const bf16x8*)&As[(wm + mi * 16 + l16) * 64 + ks + quad * 8];
#pragma unroll
      for (int ni = 0; ni < 4; ni++)
        bfr[ni] = *(const bf16x8*)&Bs[(ntoff[ni] + l16) * 64 + ks + quad * 8];
#pragma unroll
      for (int mi = 0; mi < 4; mi++)
#pragma unroll
        for (int ni = 0; ni < 4; ni++)
          acc[mi][ni] = __builtin_amdgcn_mfma_f32_16x16x32_bf16(
              af[mi], bfr[ni], acc[mi][ni], 0, 0, 0);
    }
    __syncthreads();  // all waves done reading before next gload_lds overwrite
  }

  if (!isv) {
    // epilogue: bias + RoPE (inline cos/sin)
    const int seg = (wt < 16) ? 1 : 0;  // 1=K, 0=Q
    const int head = wt & 15;
    u16* dst = seg ? Kw : Qw;
    float bv[4];
#pragma unroll
    for (int ni = 0; ni < 4; ni++)
      bv[ni] = bias[(head * 3 + seg) * 128 + ntoff[ni] + l16];
    const float RC = 0.20762050593045951f;  // log2(10000)/64
    const float f0 = exp2f(-(float)(wn + l16) * RC);
    const float f1 = exp2f(-(float)(wn + 16 + l16) * RC);

#pragma unroll
    for (int mi = 0; mi < 4; mi++) {
#pragma unroll
      for (int reg = 0; reg < 4; reg++) {
        int r = rowA0 + wm + mi * 16 + quad * 4 + reg;
        int s = r >> 1, b = r & 1;
        size_t base = ((size_t)(b * NH + head) * SEQ + s) * HD;
        float sv, cv;
        sincosf((float)s * f0, &sv, &cv);
        {
          float lo = acc[mi][0][reg] + bv[0];
          float hi = acc[mi][2][reg] + bv[2];
          dst[base + wn + l16] = f2bf(lo * cv - hi * sv);
          dst[base + wn + l16 + 64] = f2bf(hi * cv + lo * sv);
        }
        sincosf((float)s * f1, &sv, &cv);
        {
          float lo = acc[mi][1][reg] + bv[1];
          float hi = acc[mi][3][reg] + bv[3];
          dst[base + wn + 16 + l16] = f2bf(lo * cv - hi * sv);
          dst[base + wn + 16 + l16 + 64] = f2bf(hi * cv + lo * sv);
        }
      }
    }
  } else {
    const int head = wt - 32;
    float bv[4];
#pragma unroll
    for (int ni = 0; ni < 4; ni++)
      bv[ni] = bias[(head * 3 + 2) * 128 + ntoff[ni] + l16];
#pragma unroll
    for (int mi = 0; mi < 4; mi++) {
#pragma unroll
      for (int ni = 0; ni < 4; ni++) {
        int d = ntoff[ni] + l16;
#pragma unroll
        for (int reg = 0; reg < 4; reg++) {
          int r = rowA0 + wm + mi * 16 + quad * 4 + reg;
          int s = r >> 1, b = r & 1;
          Vt[((size_t)(b * NH + head) * HD + d) * SEQ + s] =
              f2bf(acc[mi][ni][reg] + bv[ni]);
        }
      }
    }
  }
}

// ---- flash attention: 8 waves x 16 q-rows, gload_lds K/V, XCD swizzle ------
__global__ __launch_bounds__(512, 4) void attn(
    const u16* __restrict__ Qw, const u16* __restrict__ Kw,
    const u16* __restrict__ Vt, u16* __restrict__ ctx) {
  __shared__ __align__(16) u16 Ks[64 * 128];          // 16384 B
  __shared__ __align__(16) u16 Vs[128 * 64 + 2304];   // 20992 B (pad: see note)
  __shared__ __align__(16) u16 Pl[8 * 16 * 72];       // 18432 B
  // total 55808 B > 160K/3 -> max 2 blocks/CU -> compiler targets 4 waves/SIMD
  // (128-VGPR class), preventing R10's 64-VGPR spill mode.

  const int tid = threadIdx.x;  // 0..511
  const int wv = tid >> 6, lane = tid & 63;
  const int quad = lane >> 4, l16 = lane & 15;

  // XCD-locality decode (R15-verified: FETCH 110->25MB): wgid%8 = XCD.
  const int lin = blockIdx.y * gridDim.x + blockIdx.x;
  const int xcdsel = lin & 7;
  const int k = lin >> 3;        // 0..63
  const int bh_hi = k >> 4;      // 0..3
  const int x = k & 15;
  const int bh = (bh_hi << 3) | xcdsel;
  const int qt = ((bh_hi >> 1) & 1) ? (15 - x) : x;

  const int b = bh >> 4, h = bh & 15;
  const int sw = qt * 128 + wv * 16;  // this wave's 16 q-rows
  const size_t bhoff = (size_t)bh * SEQ * HD;

  bf16x8 qf[4];
#pragma unroll
  for (int kc = 0; kc < 4; kc++)
    qf[kc] = *(const bf16x8*)&Qw[bhoff + (size_t)(sw + l16) * HD + kc * 32 +
                                 quad * 8];

  floatx4 o[8];
#pragma unroll
  for (int ni = 0; ni < 8; ni++) o[ni] = (floatx4){0.f, 0.f, 0.f, 0.f};
  float mst[4], lst[4];
#pragma unroll
  for (int r = 0; r < 4; r++) { mst[r] = -1e30f; lst[r] = 0.f; }

  const int nt = qt * 2 + 2;
  const float SCL2 = 0.088388347648318447f * 1.442695040888963f;
  const float MSK2 = -10000.0f * 1.442695040888963f;

// stage K/V tile tt; src pre-swizzled 16B unit u -> u^(row&7); 512 threads
// cover 1024 units each of K and V in 2 rounds.
#define STAGE(tt)                                                              \
  {                                                                            \
    _Pragma("unroll") for (int i = 0; i < 2; i++) {                            \
      int c = i * 512 + tid;                                                   \
      int rk = c >> 4, uk = c & 15;                                            \
      gl16(&Kw[bhoff + (size_t)((tt) * 64 + rk) * HD + (uk ^ (rk & 7)) * 8],   \
           &Ks[(i * 512 + wv * 64) * 8]);                                      \
      int rv_ = c >> 3, uv = c & 7;                                            \
      gl16(&Vt[bhoff + (size_t)rv_ * SEQ + (tt) * 64 + (uv ^ (rv_ & 7)) * 8],  \
           &Vs[(i * 512 + wv * 64) * 8]);                                      \
    }                                                                          \
  }

  for (int t = 0; t < nt; t++) {
    __syncthreads();  // all waves done reading Ks/Vs of prev tile
    STAGE(t);
    __syncthreads();  // drains vmcnt(0): tiles ready

    const bool active = (t * 64 <= sw + 15);
    if (active) {
      floatx4 sa[4];
#pragma unroll
      for (int ni = 0; ni < 4; ni++) sa[ni] = (floatx4){0.f, 0.f, 0.f, 0.f};
      __builtin_amdgcn_s_setprio(1);
#pragma unroll
      for (int kc = 0; kc < 4; kc++) {
        bf16x8 kf[4];
#pragma unroll
        for (int ni = 0; ni < 4; ni++)
          kf[ni] = *(const bf16x8*)&Ks[(ni * 16 + l16) * 128 +
                                       (((kc * 4 + quad) ^ (l16 & 7)) * 8)];
#pragma unroll
        for (int ni = 0; ni < 4; ni++)
          sa[ni] = __builtin_amdgcn_mfma_f32_16x16x32_bf16(qf[kc], kf[ni],
                                                           sa[ni], 0, 0, 0);
      }
      __builtin_amdgcn_s_setprio(0);

      // online softmax per row (always mask, always rescale -- R16-proven)
      float alpha[4];
#pragma unroll
      for (int reg = 0; reg < 4; reg++) {
        const int rr = quad * 4 + reg;
        const int sq = sw + rr;
        float rv[4];
#pragma unroll
        for (int ni = 0; ni < 4; ni++) {
          int sk = t * 64 + ni * 16 + l16;
          float v = sa[ni][reg] * SCL2;
          if (sk > sq) v = MSK2;
          rv[ni] = v;
        }
        float rmax = fmaxf(fmaxf(rv[0], rv[1]), fmaxf(rv[2], rv[3]));
        rmax = fmaxf(rmax, __shfl_xor(rmax, 1));
        rmax = fmaxf(rmax, __shfl_xor(rmax, 2));
        rmax = fmaxf(rmax, __shfl_xor(rmax, 4));
        rmax = fmaxf(rmax, __shfl_xor(rmax, 8));
        float mn = fmaxf(mst[reg], rmax);
        float al = exp2f(mst[reg] - mn);
        float rs = 0.f;
#pragma unroll
        for (int ni = 0; ni < 4; ni++) {
          float p = exp2f(rv[ni] - mn);
          rs += p;
          Pl[wv * 1152 + rr * 72 + ni * 16 + l16] = f2bf(p);
        }
        rs += __shfl_xor(rs, 1);
        rs += __shfl_xor(rs, 2);
        rs += __shfl_xor(rs, 4);
        rs += __shfl_xor(rs, 8);
        lst[reg] = lst[reg] * al + rs;
        mst[reg] = mn;
        alpha[reg] = al;
      }
#pragma unroll
      for (int ni = 0; ni < 8; ni++)
#pragma unroll
        for (int reg = 0; reg < 4; reg++) o[ni][reg] *= alpha[reg];

      // PV: P is wave-private (same-wave ds ordering) -> no barrier
      __builtin_amdgcn_s_setprio(1);
#pragma unroll
      for (int kc = 0; kc < 2; kc++) {
        bf16x8 pf =
            *(const bf16x8*)&Pl[wv * 1152 + l16 * 72 + kc * 32 + quad * 8];
#pragma unroll
        for (int ni = 0; ni < 8; ni++) {
          bf16x8 vf = *(const bf16x8*)&Vs[(ni * 16 + l16) * 64 +
                                          (((kc * 4 + quad) ^ (l16 & 7)) * 8)];
          o[ni] = __builtin_amdgcn_mfma_f32_16x16x32_bf16(pf, vf, o[ni], 0, 0,
                                                          0);
        }
      }
      __builtin_amdgcn_s_setprio(0);
    }
  }

  // final 1/l and store ctx [s][b][h*128+d]
#pragma unroll
  for (int reg = 0; reg < 4; reg++) {
    float inv = 1.0f / lst[reg];
    int sq = sw + quad * 4 + reg;
    size_t rbase = ((size_t)(sq * BATCH + b)) * HID + h * HD;
#pragma unroll
    for (int ni = 0; ni < 8; ni++)
      ctx[rbase + ni * 16 + l16] = f2bf(o[ni][reg] * inv);
  }
#undef STAGE
}

// -- dense GEMM split-K=2 (plain stores): ctx bf16 @ wd bf16 -----------------
// grid (16,32,2) = 1024 blocks = 4 blk/CU. Inner loop identical to R17 dense
// (16 MFMA : 8 gl16 per K-step). z=0 -> out, z=1 -> po (f32 partial).
__global__ __launch_bounds__(256, 2) void dense_gemm(
    const u16* __restrict__ A, const u16* __restrict__ Wd,
    float* __restrict__ out, float* __restrict__ po) {
  __shared__ __align__(16) u16 As[128 * 64];
  __shared__ __align__(16) u16 Bs[128 * 64];
  const int tid = threadIdx.x;
  const int wv = tid >> 6, lane = tid & 63;
  const int quad = lane >> 4, l16 = lane & 15;
  const int bn = blockIdx.x, bm = blockIdx.y;
  const int kz = blockIdx.z;
  const int rowA0 = bm * 128, rowB0 = bn * 128;
  const int wm = (wv >> 1) * 64;
  const int wn = (wv & 1) * 64;
  const int ntoff[4] = {wn, wn + 16, wn + 32, wn + 48};

  const int lrow = wv * 32 + (lane >> 3);
  const int lcol = (lane & 7) * 8;
  const u16* Ag = A + (size_t)(rowA0 + lrow) * HID + lcol;
  const u16* Bg = Wd + (size_t)(rowB0 + lrow) * HID + lcol;
  u16* Al = &As[(wv * 32) * 64];
  u16* Bl = &Bs[(wv * 32) * 64];

  floatx4 acc[4][4];
#pragma unroll
  for (int i = 0; i < 4; i++)
#pragma unroll
    for (int j = 0; j < 4; j++) acc[i][j] = (floatx4){0.f, 0.f, 0.f, 0.f};

  const int kb0 = kz * 1024;
  for (int kb = kb0; kb < kb0 + 1024; kb += 64) {
#pragma unroll
    for (int j = 0; j < 4; j++) {
      gl16(Ag + (size_t)j * 8 * HID + kb, Al + j * 8 * 64);
      gl16(Bg + (size_t)j * 8 * HID + kb, Bl + j * 8 * 64);
    }
    __syncthreads();
#pragma unroll
    for (int ks = 0; ks < 64; ks += 32) {
      bf16x8 af[4], bfr[4];
#pragma unroll
      for (int mi = 0; mi < 4; mi++)
        af[mi] = *(const bf16x8*)&As[(wm + mi * 16 + l16) * 64 + ks + quad * 8];
#pragma unroll
      for (int ni = 0; ni < 4; ni++)
        bfr[ni] = *(const bf16x8*)&Bs[(ntoff[ni] + l16) * 64 + ks + quad * 8];
#pragma unroll
      for (int mi = 0; mi < 4; mi++)
#pragma unroll
        for (int ni = 0; ni < 4; ni++)
          acc[mi][ni] = __builtin_amdgcn_mfma_f32_16x16x32_bf16(
              af[mi], bfr[ni], acc[mi][ni], 0, 0, 0);
    }
    __syncthreads();
  }

  float* dst = kz ? po : out;
#pragma unroll
  for (int mi = 0; mi < 4; mi++)
#pragma unroll
    for (int reg = 0; reg < 4; reg++) {
      int r = rowA0 + wm + mi * 16 + quad * 4 + reg;
#pragma unroll
      for (int ni = 0; ni < 4; ni++)
        dst[(size_t)r * HID + rowB0 + ntoff[ni] + l16] = acc[mi][ni][reg];
    }
}

// ---------------- combine: out += po (split-K reduction) --------------------
__global__ __launch_bounds__(256) void combine(float* __restrict__ out,
                                               const float* __restrict__ po) {
  size_t i = ((size_t)blockIdx.x * 256 + threadIdx.x) * 4;
  floatx4 a = *(const floatx4*)(out + i);
  floatx4 c = *(const floatx4*)(po + i);
  *(floatx4*)(out + i) = a + c;
}

extern "C" void kernel_launch(void* const* d_in, const int* in_sizes, int n_in,
                              void* d_out, int out_size, void* d_ws,
                              size_t ws_size, hipStream_t stream) {
  // Resolve inputs BY ELEMENT COUNT (dtype-independent):
  //   hidden 8388608, mask 4194304 (unused, precedes w_dense), w_qkv 12582912,
  //   b_qkv 6144, w_dense 4194304 (LAST match wins), b_dense 2048.
  const float *hidden = nullptr, *w_qkv = nullptr, *b_qkv = nullptr;
  const float *w_dense = nullptr, *b_dense = nullptr;
  for (int i = 0; i < n_in; i++) {
    long s = in_sizes[i];
    if (s == 8388608L) hidden = (const float*)d_in[i];
    else if (s == 12582912L) w_qkv = (const float*)d_in[i];
    else if (s == 6144L) b_qkv = (const float*)d_in[i];
    else if (s == 4194304L) w_dense = (const float*)d_in[i];  // last wins
    else if (s == 2048L) b_dense = (const float*)d_in[i];
  }
  float* out = (float*)d_out;

  // Workspace (64 MiB):
  //   [ 0,16M) Qw              ... after attn: wd [0,8M)
  //   [16,32M) Kw              ... after attn: po [16M,48M) (32MiB f32
  //   [32,48M) wb                  partial = 4096x2048x4B, exact fit)
  //   [48,64M) Ah bf16 hidden -> ctx (written by attn; dense input, LIVE)
  // d_out scratch (33.5 MB, overwritten by dense z=0 at the end):
  //   [ 0, 8M) wvw bf16 V-weight tiles (dead after qkv)
  //   [ 8,24M) Vt bf16 [b][h][d][s]    (dead after attn)
  //   tail = bias output, written by cvt_inputs, untouched after.
  char* ws = (char*)d_ws;
  u16* Qw = (u16*)(ws);                 // [ 0,16M)
  u16* Kw = (u16*)(ws + 16777216ll);    // [16,32M)
  u16* wb = (u16*)(ws + 33554432ll);    // [32,48M)
  u16* Ah = (u16*)(ws + 50331648ll);    // [48,64M) bf16 hidden (dead by attn)
  u16* ctx = (u16*)(ws + 50331648ll);   // [48,64M) after attn
  u16* wd = (u16*)(ws);                 // [0,8M) bf16 w_dense (after attn)
  float* po = (float*)(ws + 16777216ll);// [16,48M) f32 partial (after attn)
  u16* wvw = (u16*)d_out;               // d_out [0,8M)
  u16* Vt = (u16*)d_out + 4194304;      // d_out [8,24M)

  cvt_inputs<<<dim3(10241), dim3(256), 0, stream>>>(w_qkv, hidden, wb, Ah, wvw,
                                                    b_dense, out);
  qkv<<<dim3(48, 32), dim3(256), 0, stream>>>(Ah, wb, wvw, b_qkv, Qw, Kw, Vt);
  attn<<<dim3(16, 32), dim3(512), 0, stream>>>(Qw, Kw, Vt, ctx);
  cvt_wd<<<dim3(2048), dim3(256), 0, stream>>>(w_dense, wd);
  dense_gemm<<<dim3(16, 32, 2), dim3(256), 0, stream>>>(ctx, wd, out, po);
  combine<<<dim3(8192), dim3(256), 0, stream>>>(out, po);
}

// Round 13
// 425.782 us; speedup vs baseline: 1.0300x; 1.0300x over previous
//
#include <hip/hip_runtime.h>
#include <cstdint>
#include <math.h>

// ---------------------------------------------------------------------------
// ParallelAttention (GPT-NeoX style), MI355X gfx950.
//   SEQ=2048 BATCH=2 HID=2048 NH=16 HD=128, causal mask, RoPE full head dim.
// INTERFACE (established R0-R7): fp32 inputs, fp32 output, inputs resolved by
//   element count (w_dense = LAST 4194304 match; mask unused).
// R9: GEMMs on m97 structure (bf16 pre-convert + global_load_lds w16).
// R11/R15/R16: attn single-buffer + XCD-locality swizzle (FETCH 110->25MB).
// R17: 8-wave attn + merged qkv: 422.1 (best). R18/R19/R20 dense attempts
//   all regressed. R21 ledger reconciliation (via m102 N=2048 ~320TF):
//   cvt 18 + qkv 148 + attn 133 + cvt_wd 6 + dense 107 = 422 (R17) and
//   438.6 = same + combine 17 (R20). KEY: R17's 8-wave attn change was
//   NEUTRAL (attn still ~133); R20's split-K never reached 4 blk/CU because
//   blockIdx.z varies SLOWEST (all kz=0 dispatched before kz=1).
// R21: (1) dense split-K with kz in FASTEST dim: dim3(2,16,32), x=kz ->
//   the two K-halves of each tile are consecutive in dispatch -> co-resident
//   -> true 4 blk/CU at the proven 16:8 tile ratio. Plain stores + combine.
//   (2) qkv RoPE epilogue by angle-addition: 6 sincosf + rotations replaces
//   32 sincosf (s = S0+q2+(reg>>1)+8mi; 2 chains/freq rotated by 8f per mi).
//   (3) attn P-store via native __bf16 cast (HW RNE, 1 op) vs 3-op f2bf.
// MFMA 16x16x32 bf16: A/B row=lane&15, k=(lane>>4)*8+j; C/D col=lane&15,
//   row=(lane>>4)*4+reg (verified m89/m91).
// global_load_lds: LDS dest is wave-uniform base + lane*16B (m104/m108) --
//   LDS must be LINEAR, source address is per-lane (pre-swizzle there).
// ---------------------------------------------------------------------------

typedef unsigned short u16;
typedef __bf16 bf16x8 __attribute__((ext_vector_type(8)));
typedef float floatx4 __attribute__((ext_vector_type(4)));

#define SEQ 2048
#define BATCH 2
#define HID 2048
#define NH 16
#define HD 128

__device__ __forceinline__ u16 f2bf(float f) {
  union { float f; uint32_t u; } v; v.f = f;
  uint32_t u = v.u;
  return (u16)((u + 0x7FFFu + ((u >> 16) & 1u)) >> 16);
}

// pack 8 fp32 -> 8 bf16 (RNE) and store 16B
__device__ __forceinline__ void st8_bf16(u16* dst, const float* s) {
  uint32_t pk[4];
#pragma unroll
  for (int j = 0; j < 4; j++)
    pk[j] = (uint32_t)f2bf(s[2 * j]) | ((uint32_t)f2bf(s[2 * j + 1]) << 16);
  *(uint4*)dst = make_uint4(pk[0], pk[1], pk[2], pk[3]);
}

// async global->LDS, 16B per lane; lds base must be wave-uniform
__device__ __forceinline__ void gl16(const u16* g, u16* l) {
  __builtin_amdgcn_global_load_lds(
      (const __attribute__((address_space(1))) void*)g,
      (__attribute__((address_space(3))) void*)l, 16, 0, 0);
}

// rotate (c,s) by angle delta with precomputed (cd,sd)
__device__ __forceinline__ void rot2(float& c, float& s, float cd, float sd) {
  float t = c * cd - s * sd;
  s = s * cd + c * sd;
  c = t;
}

// ------- input conversion: w_qkv K/Q tiles, hidden, V tiles; + bias tail ----
// wb tile order: [K head 0..15][Q head 0..15]; src K h = 3h+1, Q h = 3h.
// V tiles (blk 8192..10239) -> wvw (d_out scratch). blk 10240 = bias tail.
__global__ __launch_bounds__(256) void cvt_inputs(
    const float* __restrict__ W, const float* __restrict__ Hid,
    u16* __restrict__ wb, u16* __restrict__ Ah, u16* __restrict__ wvw,
    const float* __restrict__ bd, float* __restrict__ out) {
  const int blk = blockIdx.x;
  const int c0 = threadIdx.x * 8;
  if (blk == 10240) {  // bias passthrough: fp32 -> out tail (never clobbered)
#pragma unroll
    for (int j = 0; j < 8; j++)
      out[(size_t)SEQ * BATCH * HID + c0 + j] = bd[c0 + j];
    return;
  }
  const float* src;
  u16* dst;
  if (blk < 4096) {
    int dt = blk >> 7, r = blk & 127;
    int srow = (dt < 16) ? ((dt * 3 + 1) * 128 + r) : (((dt - 16) * 3) * 128 + r);
    src = W + (size_t)srow * HID;
    dst = wb + (size_t)blk * HID;
  } else if (blk < 8192) {
    int r = blk - 4096;
    src = Hid + (size_t)r * HID;
    dst = Ah + (size_t)r * HID;
  } else {
    int v = blk - 8192;  // 0..2047
    int h = v >> 7, r = v & 127;
    src = W + (size_t)((h * 3 + 2) * 128 + r) * HID;
    dst = wvw + (size_t)v * HID;
  }
  float t[8];
  *(floatx4*)&t[0] = *(const floatx4*)(src + c0);
  *(floatx4*)&t[4] = *(const floatx4*)(src + c0 + 4);
  st8_bf16(dst + c0, t);
}

// ---------------- w_dense fp32 -> bf16 (after attn: wd aliases Qw) ----------
__global__ __launch_bounds__(256) void cvt_wd(const float* __restrict__ W,
                                              u16* __restrict__ wd) {
  const int r = blockIdx.x;
  const int c0 = threadIdx.x * 8;
  float t[8];
  const float* src = W + (size_t)r * HID;
  *(floatx4*)&t[0] = *(const floatx4*)(src + c0);
  *(floatx4*)&t[4] = *(const floatx4*)(src + c0 + 4);
  st8_bf16(wd + (size_t)r * HID + c0, t);
}

// ------- QKV projection (merged): bf16 @ bf16, gload_lds both operands ------
// blockIdx.x 0..15 = K head, 16..31 = Q head, 32..47 = V head.
__global__ __launch_bounds__(256, 2) void qkv(
    const u16* __restrict__ Ah, const u16* __restrict__ wb,
    const u16* __restrict__ wvw, const float* __restrict__ bias,
    u16* __restrict__ Qw, u16* __restrict__ Kw, u16* __restrict__ Vt) {
  __shared__ __align__(16) u16 As[128 * 64];
  __shared__ __align__(16) u16 Bs[128 * 64];
  const int tid = threadIdx.x;
  const int wv = tid >> 6, lane = tid & 63;
  const int quad = lane >> 4, l16 = lane & 15;
  const int wt = blockIdx.x;  // 0..47
  const bool isv = (wt >= 32);
  const int bm = blockIdx.y;
  const int rowA0 = bm * 128;
  const int wm = (wv >> 1) * 64;
  const int wn = (wv & 1) * 32;
  const int ntoff[4] = {wn, wn + 16, wn + 64, wn + 80};

  const int lrow = wv * 32 + (lane >> 3);
  const int lcol = (lane & 7) * 8;
  const u16* Ag = Ah + (size_t)(rowA0 + lrow) * HID + lcol;
  const u16* Bg = (isv ? wvw + ((size_t)(wt - 32) * 128 + lrow) * HID
                       : wb + ((size_t)wt * 128 + lrow) * HID) + lcol;
  u16* Al = &As[(wv * 32) * 64];  // wave-uniform
  u16* Bl = &Bs[(wv * 32) * 64];

  floatx4 acc[4][4];
#pragma unroll
  for (int i = 0; i < 4; i++)
#pragma unroll
    for (int j = 0; j < 4; j++) acc[i][j] = (floatx4){0.f, 0.f, 0.f, 0.f};

  for (int kb = 0; kb < HID; kb += 64) {
#pragma unroll
    for (int j = 0; j < 4; j++) {
      gl16(Ag + (size_t)j * 8 * HID + kb, Al + j * 8 * 64);
      gl16(Bg + (size_t)j * 8 * HID + kb, Bl + j * 8 * 64);
    }
    __syncthreads();  // drains vmcnt(0): LDS tiles ready
#pragma unroll
    for (int ks = 0; ks < 64; ks += 32) {
      bf16x8 af[4], bfr[4];
#pragma unroll
      for (int mi = 0; mi < 4; mi++)
        af[mi] = *(const bf16x8*)&As[(wm + mi * 16 + l16) * 64 + ks + quad * 8];
#pragma unroll
      for (int ni = 0; ni < 4; ni++)
        bfr[ni] = *(const bf16x8*)&Bs[(ntoff[ni] + l16) * 64 + ks + quad * 8];
#pragma unroll
      for (int mi = 0; mi < 4; mi++)
#pragma unroll
        for (int ni = 0; ni < 4; ni++)
          acc[mi][ni] = __builtin_amdgcn_mfma_f32_16x16x32_bf16(
              af[mi], bfr[ni], acc[mi][ni], 0, 0, 0);
    }
    __syncthreads();  // all waves done reading before next gload_lds overwrite
  }

  if (!isv) {
    // epilogue: bias + RoPE. Angle-addition: per thread s = S0+q2+(reg>>1)+8mi
    // (b = reg&1). Two chains per freq (reg<2 and reg>=2), rotated by 8f/mi.
    const int seg = (wt < 16) ? 1 : 0;  // 1=K, 0=Q
    const int head = wt & 15;
    u16* dst = seg ? Kw : Qw;
    float bv[4];
#pragma unroll
    for (int ni = 0; ni < 4; ni++)
      bv[ni] = bias[(head * 3 + seg) * 128 + ntoff[ni] + l16];
    const float RC = 0.20762050593045951f;  // log2(10000)/64
    const float f0 = exp2f(-(float)(wn + l16) * RC);
    const float f1 = exp2f(-(float)(wn + 16 + l16) * RC);
    const int S0 = (rowA0 + wm) >> 1;
    const int q2 = quad * 2;
    float cA0, sA0, cB0, sB0, c80, s80;
    float cA1, sA1, cB1, sB1, c81, s81;
    sincosf((float)(S0 + q2) * f0, &sA0, &cA0);
    sincosf((float)(S0 + q2 + 1) * f0, &sB0, &cB0);
    sincosf(8.0f * f0, &s80, &c80);
    sincosf((float)(S0 + q2) * f1, &sA1, &cA1);
    sincosf((float)(S0 + q2 + 1) * f1, &sB1, &cB1);
    sincosf(8.0f * f1, &s81, &c81);

#pragma unroll
    for (int mi = 0; mi < 4; mi++) {
#pragma unroll
      for (int reg = 0; reg < 4; reg++) {
        int r = rowA0 + wm + mi * 16 + quad * 4 + reg;
        int s = r >> 1, b = r & 1;
        size_t base = ((size_t)(b * NH + head) * SEQ + s) * HD;
        float cv0 = (reg < 2) ? cA0 : cB0;
        float sv0 = (reg < 2) ? sA0 : sB0;
        float cv1 = (reg < 2) ? cA1 : cB1;
        float sv1 = (reg < 2) ? sA1 : sB1;
        {
          float lo = acc[mi][0][reg] + bv[0];
          float hi = acc[mi][2][reg] + bv[2];
          dst[base + wn + l16] = f2bf(lo * cv0 - hi * sv0);
          dst[base + wn + l16 + 64] = f2bf(hi * cv0 + lo * sv0);
        }
        {
          float lo = acc[mi][1][reg] + bv[1];
          float hi = acc[mi][3][reg] + bv[3];
          dst[base + wn + 16 + l16] = f2bf(lo * cv1 - hi * sv1);
          dst[base + wn + 16 + l16 + 64] = f2bf(hi * cv1 + lo * sv1);
        }
      }
      rot2(cA0, sA0, c80, s80);
      rot2(cB0, sB0, c80, s80);
      rot2(cA1, sA1, c81, s81);
      rot2(cB1, sB1, c81, s81);
    }
  } else {
    const int head = wt - 32;
    float bv[4];
#pragma unroll
    for (int ni = 0; ni < 4; ni++)
      bv[ni] = bias[(head * 3 + 2) * 128 + ntoff[ni] + l16];
#pragma unroll
    for (int mi = 0; mi < 4; mi++) {
#pragma unroll
      for (int ni = 0; ni < 4; ni++) {
        int d = ntoff[ni] + l16;
#pragma unroll
        for (int reg = 0; reg < 4; reg++) {
          int r = rowA0 + wm + mi * 16 + quad * 4 + reg;
          int s = r >> 1, b = r & 1;
          Vt[((size_t)(b * NH + head) * HD + d) * SEQ + s] =
              f2bf(acc[mi][ni][reg] + bv[ni]);
        }
      }
    }
  }
}

// ---- flash attention: 8 waves x 16 q-rows, gload_lds K/V, XCD swizzle ------
__global__ __launch_bounds__(512, 4) void attn(
    const u16* __restrict__ Qw, const u16* __restrict__ Kw,
    const u16* __restrict__ Vt, u16* __restrict__ ctx) {
  __shared__ __align__(16) u16 Ks[64 * 128];          // 16384 B
  __shared__ __align__(16) u16 Vs[128 * 64 + 2304];   // 20992 B (pad: see note)
  __shared__ __align__(16) u16 Pl[8 * 16 * 72];       // 18432 B
  // total 55808 B > 160K/3 -> max 2 blocks/CU -> compiler targets 4 waves/SIMD
  // (128-VGPR class), preventing R10's 64-VGPR spill mode.

  const int tid = threadIdx.x;  // 0..511
  const int wv = tid >> 6, lane = tid & 63;
  const int quad = lane >> 4, l16 = lane & 15;

  // XCD-locality decode (R15-verified: FETCH 110->25MB): wgid%8 = XCD.
  const int lin = blockIdx.y * gridDim.x + blockIdx.x;
  const int xcdsel = lin & 7;
  const int k = lin >> 3;        // 0..63
  const int bh_hi = k >> 4;      // 0..3
  const int x = k & 15;
  const int bh = (bh_hi << 3) | xcdsel;
  const int qt = ((bh_hi >> 1) & 1) ? (15 - x) : x;

  const int b = bh >> 4, h = bh & 15;
  const int sw = qt * 128 + wv * 16;  // this wave's 16 q-rows
  const size_t bhoff = (size_t)bh * SEQ * HD;

  bf16x8 qf[4];
#pragma unroll
  for (int kc = 0; kc < 4; kc++)
    qf[kc] = *(const bf16x8*)&Qw[bhoff + (size_t)(sw + l16) * HD + kc * 32 +
                                 quad * 8];

  floatx4 o[8];
#pragma unroll
  for (int ni = 0; ni < 8; ni++) o[ni] = (floatx4){0.f, 0.f, 0.f, 0.f};
  float mst[4], lst[4];
#pragma unroll
  for (int r = 0; r < 4; r++) { mst[r] = -1e30f; lst[r] = 0.f; }

  const int nt = qt * 2 + 2;
  const float SCL2 = 0.088388347648318447f * 1.442695040888963f;
  const float MSK2 = -10000.0f * 1.442695040888963f;

// stage K/V tile tt; src pre-swizzled 16B unit u -> u^(row&7); 512 threads
// cover 1024 units each of K and V in 2 rounds.
#define STAGE(tt)                                                              \
  {                                                                            \
    _Pragma("unroll") for (int i = 0; i < 2; i++) {                            \
      int c = i * 512 + tid;                                                   \
      int rk = c >> 4, uk = c & 15;                                            \
      gl16(&Kw[bhoff + (size_t)((tt) * 64 + rk) * HD + (uk ^ (rk & 7)) * 8],   \
           &Ks[(i * 512 + wv * 64) * 8]);                                      \
      int rv_ = c >> 3, uv = c & 7;                                            \
      gl16(&Vt[bhoff + (size_t)rv_ * SEQ + (tt) * 64 + (uv ^ (rv_ & 7)) * 8],  \
           &Vs[(i * 512 + wv * 64) * 8]);                                      \
    }                                                                          \
  }

  for (int t = 0; t < nt; t++) {
    __syncthreads();  // all waves done reading Ks/Vs of prev tile
    STAGE(t);
    __syncthreads();  // drains vmcnt(0): tiles ready

    const bool active = (t * 64 <= sw + 15);
    if (active) {
      floatx4 sa[4];
#pragma unroll
      for (int ni = 0; ni < 4; ni++) sa[ni] = (floatx4){0.f, 0.f, 0.f, 0.f};
      __builtin_amdgcn_s_setprio(1);
#pragma unroll
      for (int kc = 0; kc < 4; kc++) {
        bf16x8 kf[4];
#pragma unroll
        for (int ni = 0; ni < 4; ni++)
          kf[ni] = *(const bf16x8*)&Ks[(ni * 16 + l16) * 128 +
                                       (((kc * 4 + quad) ^ (l16 & 7)) * 8)];
#pragma unroll
        for (int ni = 0; ni < 4; ni++)
          sa[ni] = __builtin_amdgcn_mfma_f32_16x16x32_bf16(qf[kc], kf[ni],
                                                           sa[ni], 0, 0, 0);
      }
      __builtin_amdgcn_s_setprio(0);

      // online softmax per row (always mask, always rescale -- R16-proven)
      float alpha[4];
#pragma unroll
      for (int reg = 0; reg < 4; reg++) {
        const int rr = quad * 4 + reg;
        const int sq = sw + rr;
        float rv[4];
#pragma unroll
        for (int ni = 0; ni < 4; ni++) {
          int sk = t * 64 + ni * 16 + l16;
          float v = sa[ni][reg] * SCL2;
          if (sk > sq) v = MSK2;
          rv[ni] = v;
        }
        float rmax = fmaxf(fmaxf(rv[0], rv[1]), fmaxf(rv[2], rv[3]));
        rmax = fmaxf(rmax, __shfl_xor(rmax, 1));
        rmax = fmaxf(rmax, __shfl_xor(rmax, 2));
        rmax = fmaxf(rmax, __shfl_xor(rmax, 4));
        rmax = fmaxf(rmax, __shfl_xor(rmax, 8));
        float mn = fmaxf(mst[reg], rmax);
        float al = exp2f(mst[reg] - mn);
        float rs = 0.f;
#pragma unroll
        for (int ni = 0; ni < 4; ni++) {
          float p = exp2f(rv[ni] - mn);
          rs += p;
          // native bf16 cast: HW RNE cvt (1 op) vs 3-op manual f2bf
          ((__bf16*)Pl)[wv * 1152 + rr * 72 + ni * 16 + l16] = (__bf16)p;
        }
        rs += __shfl_xor(rs, 1);
        rs += __shfl_xor(rs, 2);
        rs += __shfl_xor(rs, 4);
        rs += __shfl_xor(rs, 8);
        lst[reg] = lst[reg] * al + rs;
        mst[reg] = mn;
        alpha[reg] = al;
      }
#pragma unroll
      for (int ni = 0; ni < 8; ni++)
#pragma unroll
        for (int reg = 0; reg < 4; reg++) o[ni][reg] *= alpha[reg];

      // PV: P is wave-private (same-wave ds ordering) -> no barrier
      __builtin_amdgcn_s_setprio(1);
#pragma unroll
      for (int kc = 0; kc < 2; kc++) {
        bf16x8 pf =
            *(const bf16x8*)&Pl[wv * 1152 + l16 * 72 + kc * 32 + quad * 8];
#pragma unroll
        for (int ni = 0; ni < 8; ni++) {
          bf16x8 vf = *(const bf16x8*)&Vs[(ni * 16 + l16) * 64 +
                                          (((kc * 4 + quad) ^ (l16 & 7)) * 8)];
          o[ni] = __builtin_amdgcn_mfma_f32_16x16x32_bf16(pf, vf, o[ni], 0, 0,
                                                          0);
        }
      }
      __builtin_amdgcn_s_setprio(0);
    }
  }

  // final 1/l and store ctx [s][b][h*128+d]
#pragma unroll
  for (int reg = 0; reg < 4; reg++) {
    float inv = 1.0f / lst[reg];
    int sq = sw + quad * 4 + reg;
    size_t rbase = ((size_t)(sq * BATCH + b)) * HID + h * HD;
#pragma unroll
    for (int ni = 0; ni < 8; ni++)
      ctx[rbase + ni * 16 + l16] = f2bf(o[ni][reg] * inv);
  }
#undef STAGE
}

// -- dense GEMM split-K=2, kz in FASTEST dim: both halves co-resident --------
// grid dim3(2,16,32): x=kz, y=bn, z=bm -> consecutive dispatch = both K
// halves of one tile -> true 4 blk/CU. Inner loop = R17 (16 MFMA : 8 gl16).
__global__ __launch_bounds__(256, 2) void dense_gemm(
    const u16* __restrict__ A, const u16* __restrict__ Wd,
    float* __restrict__ out, float* __restrict__ po) {
  __shared__ __align__(16) u16 As[128 * 64];
  __shared__ __align__(16) u16 Bs[128 * 64];
  const int tid = threadIdx.x;
  const int wv = tid >> 6, lane = tid & 63;
  const int quad = lane >> 4, l16 = lane & 15;
  const int kz = blockIdx.x;
  const int bn = blockIdx.y, bm = blockIdx.z;
  const int rowA0 = bm * 128, rowB0 = bn * 128;
  const int wm = (wv >> 1) * 64;
  const int wn = (wv & 1) * 64;
  const int ntoff[4] = {wn, wn + 16, wn + 32, wn + 48};

  const int lrow = wv * 32 + (lane >> 3);
  const int lcol = (lane & 7) * 8;
  const u16* Ag = A + (size_t)(rowA0 + lrow) * HID + lcol;
  const u16* Bg = Wd + (size_t)(rowB0 + lrow) * HID + lcol;
  u16* Al = &As[(wv * 32) * 64];
  u16* Bl = &Bs[(wv * 32) * 64];

  floatx4 acc[4][4];
#pragma unroll
  for (int i = 0; i < 4; i++)
#pragma unroll
    for (int j = 0; j < 4; j++) acc[i][j] = (floatx4){0.f, 0.f, 0.f, 0.f};

  const int kb0 = kz * 1024;
  for (int kb = kb0; kb < kb0 + 1024; kb += 64) {
#pragma unroll
    for (int j = 0; j < 4; j++) {
      gl16(Ag + (size_t)j * 8 * HID + kb, Al + j * 8 * 64);
      gl16(Bg + (size_t)j * 8 * HID + kb, Bl + j * 8 * 64);
    }
    __syncthreads();
#pragma unroll
    for (int ks = 0; ks < 64; ks += 32) {
      bf16x8 af[4], bfr[4];
#pragma unroll
      for (int mi = 0; mi < 4; mi++)
        af[mi] = *(const bf16x8*)&As[(wm + mi * 16 + l16) * 64 + ks + quad * 8];
#pragma unroll
      for (int ni = 0; ni < 4; ni++)
        bfr[ni] = *(const bf16x8*)&Bs[(ntoff[ni] + l16) * 64 + ks + quad * 8];
#pragma unroll
      for (int mi = 0; mi < 4; mi++)
#pragma unroll
        for (int ni = 0; ni < 4; ni++)
          acc[mi][ni] = __builtin_amdgcn_mfma_f32_16x16x32_bf16(
              af[mi], bfr[ni], acc[mi][ni], 0, 0, 0);
    }
    __syncthreads();
  }

  float* dst = kz ? po : out;
#pragma unroll
  for (int mi = 0; mi < 4; mi++)
#pragma unroll
    for (int reg = 0; reg < 4; reg++) {
      int r = rowA0 + wm + mi * 16 + quad * 4 + reg;
#pragma unroll
      for (int ni = 0; ni < 4; ni++)
        dst[(size_t)r * HID + rowB0 + ntoff[ni] + l16] = acc[mi][ni][reg];
    }
}

// ---------------- combine: out += po (split-K reduction) --------------------
__global__ __launch_bounds__(256) void combine(float* __restrict__ out,
                                               const float* __restrict__ po) {
  size_t i = ((size_t)blockIdx.x * 256 + threadIdx.x) * 4;
  floatx4 a = *(const floatx4*)(out + i);
  floatx4 c = *(const floatx4*)(po + i);
  *(floatx4*)(out + i) = a + c;
}

extern "C" void kernel_launch(void* const* d_in, const int* in_sizes, int n_in,
                              void* d_out, int out_size, void* d_ws,
                              size_t ws_size, hipStream_t stream) {
  // Resolve inputs BY ELEMENT COUNT (dtype-independent):
  //   hidden 8388608, mask 4194304 (unused, precedes w_dense), w_qkv 12582912,
  //   b_qkv 6144, w_dense 4194304 (LAST match wins), b_dense 2048.
  const float *hidden = nullptr, *w_qkv = nullptr, *b_qkv = nullptr;
  const float *w_dense = nullptr, *b_dense = nullptr;
  for (int i = 0; i < n_in; i++) {
    long s = in_sizes[i];
    if (s == 8388608L) hidden = (const float*)d_in[i];
    else if (s == 12582912L) w_qkv = (const float*)d_in[i];
    else if (s == 6144L) b_qkv = (const float*)d_in[i];
    else if (s == 4194304L) w_dense = (const float*)d_in[i];  // last wins
    else if (s == 2048L) b_dense = (const float*)d_in[i];
  }
  float* out = (float*)d_out;

  // Workspace (64 MiB):
  //   [ 0,16M) Qw              ... after attn: wd [0,8M)
  //   [16,32M) Kw              ... after attn: po [16M,48M) (32MiB f32
  //   [32,48M) wb                  partial = 4096x2048x4B, exact fit)
  //   [48,64M) Ah bf16 hidden -> ctx (written by attn; dense input, LIVE)
  // d_out scratch (33.5 MB, overwritten by dense z=0 at the end):
  //   [ 0, 8M) wvw bf16 V-weight tiles (dead after qkv)
  //   [ 8,24M) Vt bf16 [b][h][d][s]    (dead after attn)
  //   tail = bias output, written by cvt_inputs, untouched after.
  char* ws = (char*)d_ws;
  u16* Qw = (u16*)(ws);                 // [ 0,16M)
  u16* Kw = (u16*)(ws + 16777216ll);    // [16,32M)
  u16* wb = (u16*)(ws + 33554432ll);    // [32,48M)
  u16* Ah = (u16*)(ws + 50331648ll);    // [48,64M) bf16 hidden (dead by attn)
  u16* ctx = (u16*)(ws + 50331648ll);   // [48,64M) after attn
  u16* wd = (u16*)(ws);                 // [0,8M) bf16 w_dense (after attn)
  float* po = (float*)(ws + 16777216ll);// [16,48M) f32 partial (after attn)
  u16* wvw = (u16*)d_out;               // d_out [0,8M)
  u16* Vt = (u16*)d_out + 4194304;      // d_out [8,24M)

  cvt_inputs<<<dim3(10241), dim3(256), 0, stream>>>(w_qkv, hidden, wb, Ah, wvw,
                                                    b_dense, out);
  qkv<<<dim3(48, 32), dim3(256), 0, stream>>>(Ah, wb, wvw, b_qkv, Qw, Kw, Vt);
  attn<<<dim3(16, 32), dim3(512), 0, stream>>>(Qw, Kw, Vt, ctx);
  cvt_wd<<<dim3(2048), dim3(256), 0, stream>>>(w_dense, wd);
  dense_gemm<<<dim3(2, 16, 32), dim3(256), 0, stream>>>(ctx, wd, out, po);
  combine<<<dim3(8192), dim3(256), 0, stream>>>(out, po);
}